// Round 2
// baseline (1163.726 us; speedup 1.0000x reference)
//
#include <hip/hip_runtime.h>
#include <math.h>

// Problem constants
#define KCODES 1024
#define DIMV   64
#define NROWS  131072   // 32*64*64
#define HWSZ   4096     // 64*64
#define NELEM  8388608  // 32*64*64*64

// ws layout (bytes):
//   0      : double loss_sum          (8)
//   8      : int    counts[1024]      (4096)
//   4104   : float  dw[65536]         (262144)
//   266248 : float  s_w[1024]         (4096)    fp32 |w_k|^2, numpy pairwise order
// zeroed region = first 266248 bytes

// numpy scalar pairwise path for n=64 contiguous: r[j] = fl(v[j]^2), then
// sequential r[j] += fl(v[8m+j]^2) for m=1..7, combined
// ((r0+r1)+(r2+r3)) + ((r4+r5)+(r6+r7)).  asm barrier stops hipcc's
// -ffp-contract=fast from fusing square+add into fma (numpy rounds twice).
__global__ __launch_bounds__(256) void vq_prep_kernel(
    const float* __restrict__ emb, float* __restrict__ s_w)
{
    int k = blockIdx.x * 256 + threadIdx.x;   // grid 4*256 = 1024 codes
    const float* v = emb + k * DIMV;
    float r[8];
    #pragma unroll
    for (int j = 0; j < 8; ++j) {
        float sq = v[j] * v[j];
        asm("" : "+v"(sq));
        r[j] = sq;
    }
    #pragma unroll
    for (int m = 1; m < 8; ++m) {
        #pragma unroll
        for (int j = 0; j < 8; ++j) {
            float sq = v[8 * m + j] * v[8 * m + j];
            asm("" : "+v"(sq));
            r[j] += sq;
        }
    }
    s_w[k] = ((r[0] + r[1]) + (r[2] + r[3])) + ((r[4] + r[5]) + (r[6] + r[7]));
}

__global__ __launch_bounds__(256) void vq_assign_kernel(
    const float* __restrict__ inp, const float* __restrict__ emb,
    const float* __restrict__ s_w,
    float* __restrict__ q_out, float* __restrict__ enc_out,
    double* __restrict__ loss_sum, int* __restrict__ counts,
    float* __restrict__ dw)
{
    int n  = blockIdx.x * 256 + threadIdx.x;   // row id in [0, NROWS)
    int b  = n >> 12;                          // batch
    int hw = n & 4095;                         // h*64 + w

    // f_i = inputs[b][i][h][w]; keep g = 2f (exact, = numpy's 2.0*flat).
    const float* fin = inp + (size_t)b * DIMV * HWSZ + hw;
    float g[DIMV];
    #pragma unroll
    for (int i = 0; i < DIMV; ++i) {
        float fi = fin[(size_t)i * HWSZ];
        g[i] = fi + fi;
    }

    // s_f = numpy pairwise fp32 of fl(f_i^2); f_i = 0.5*g[i] exactly.
    float r[8];
    #pragma unroll
    for (int j = 0; j < 8; ++j) {
        float h = 0.5f * g[j];
        float sq = h * h;
        asm("" : "+v"(sq));
        r[j] = sq;
    }
    #pragma unroll
    for (int m = 1; m < 8; ++m) {
        #pragma unroll
        for (int j = 0; j < 8; ++j) {
            float h = 0.5f * g[8 * m + j];
            float sq = h * h;
            asm("" : "+v"(sq));
            r[j] += sq;
        }
    }
    float sf = ((r[0] + r[1]) + (r[2] + r[3])) + ((r[4] + r[5]) + (r[6] + r[7]));

    // d_k = fl32( fl32(sf - P_k) + s_w_k ),  P_k = sequential fp32 fma chain
    // over i ascending of (2f_i)*w_ki  (replicates OpenBLAS sgemm k-order).
    // argmin with strict < : first index wins, matching np.argmin.
    float best = 3.0e38f;
    int bestk = 0;
    for (int k = 0; k < KCODES; ++k) {
        const float* wk = emb + k * DIMV;      // wave-uniform -> scalar loads
        float acc = 0.0f;
        #pragma unroll
        for (int i = 0; i < DIMV; ++i)
            acc = __builtin_fmaf(g[i], wk[i], acc);
        float t  = sf - acc;
        float dk = t + s_w[k];
        if (dk < best) { best = dk; bestk = k; }
    }

    enc_out[n] = (float)bestk;
    atomicAdd(&counts[bestk], 1);

    // q_out[b][i][h][w] = emb_w[bestk][i]  (exact fp32 copy)
    const float* wrow = emb + bestk * DIMV;
    float* qo = q_out + (size_t)b * DIMV * HWSZ + hw;
    double l = 0.0;
    #pragma unroll
    for (int i = 0; i < DIMV; ++i) {
        float q = wrow[i];
        qo[(size_t)i * HWSZ] = q;
        float h = 0.5f * g[i];
        double dq = (double)q - (double)h;
        l = fma(dq, dq, l);
        atomicAdd(&dw[bestk * DIMV + i], h);
    }

    __shared__ double sm[256];
    sm[threadIdx.x] = l;
    __syncthreads();
    #pragma unroll
    for (int off = 128; off > 0; off >>= 1) {
        if (threadIdx.x < off) sm[threadIdx.x] += sm[threadIdx.x + off];
        __syncthreads();
    }
    if (threadIdx.x == 0) atomicAdd(loss_sum, sm[0]);
}

__global__ __launch_bounds__(1024) void vq_finalize_kernel(
    const float* __restrict__ ema_cs, const float* __restrict__ ema_w,
    const int* __restrict__ counts, const float* __restrict__ dw,
    const double* __restrict__ loss_sum,
    float* __restrict__ out_loss, float* __restrict__ out_nll,
    float* __restrict__ out_ncs, float* __restrict__ out_nema,
    float* __restrict__ out_nemb)
{
    int k = threadIdx.x;   // one thread per code
    const double DECAY = 0.99;
    const double OMD   = 1.0 - 0.99;
    const double EPSV  = 1e-5;

    double ncs = (double)ema_cs[k] * DECAY + OMD * (double)counts[k];

    __shared__ double sm[1024];
    sm[k] = ncs;
    __syncthreads();
    #pragma unroll
    for (int off = 512; off > 0; off >>= 1) {
        if (k < off) sm[k] += sm[k + off];
        __syncthreads();
    }
    double nsum = sm[0];
    double adj = (ncs + EPSV) / (nsum + (double)KCODES * EPSV) * nsum;
    out_ncs[k] = (float)adj;

    #pragma unroll
    for (int i = 0; i < DIMV; ++i) {
        double ne = (double)ema_w[k * DIMV + i] * DECAY
                  + OMD * (double)dw[k * DIMV + i];
        out_nema[k * DIMV + i] = (float)ne;
        out_nemb[k * DIMV + i] = (float)(ne / adj);
    }

    if (k == 0) {
        double e = loss_sum[0] / (double)NELEM;
        out_loss[0] = (float)(e + 0.25 * e);
        out_nll[0]  = 1.0f;
    }
}

extern "C" void kernel_launch(void* const* d_in, const int* in_sizes, int n_in,
                              void* d_out, int out_size, void* d_ws, size_t ws_size,
                              hipStream_t stream) {
    const float* inp    = (const float*)d_in[0];  // (32,64,64,64) NCHW
    const float* emb    = (const float*)d_in[1];  // (1024,64)
    const float* ema_cs = (const float*)d_in[2];  // (1024,)
    const float* ema_w  = (const float*)d_in[3];  // (1024,64)

    char* ws = (char*)d_ws;
    double* loss_sum = (double*)(ws + 0);
    int*    counts   = (int*)   (ws + 8);
    float*  dw       = (float*) (ws + 4104);
    float*  s_w      = (float*) (ws + 266248);

    float* out       = (float*)d_out;
    float* q_out     = out;                       // 8388608
    float* enc_out   = out + 8388608;             // 131072
    float* out_loss  = out + 8519680;             // 1
    float* out_nll   = out + 8519681;             // 1
    float* out_ncs   = out + 8519682;             // 1024
    float* out_nema  = out + 8520706;             // 65536
    float* out_nemb  = out + 8586242;             // 65536

    hipMemsetAsync(ws, 0, 266248, stream);
    hipLaunchKernelGGL(vq_prep_kernel, dim3(4), dim3(256), 0, stream,
                       emb, s_w);
    hipLaunchKernelGGL(vq_assign_kernel, dim3(NROWS / 256), dim3(256), 0, stream,
                       inp, emb, s_w, q_out, enc_out, loss_sum, counts, dw);
    hipLaunchKernelGGL(vq_finalize_kernel, dim3(1), dim3(1024), 0, stream,
                       ema_cs, ema_w, counts, dw, loss_sum,
                       out_loss, out_nll, out_ncs, out_nema, out_nemb);
}

// Round 3
// 797.351 us; speedup vs baseline: 1.4595x; 1.4595x over previous
//
#include <hip/hip_runtime.h>
#include <math.h>

// Problem constants
#define KCODES 1024
#define DIMV   64
#define NROWS  131072   // 32*64*64
#define HWSZ   4096     // 64*64
#define NELEM  8388608  // 32*64*64*64

// ws layout (bytes):
//   0      : double loss_sum          (8)
//   8      : int    counts[1024]      (4096)
//   4104   : float  dw[65536]         (262144)
//   266248 : float  s_w[1024]         (4096)    fp32 |w_k|^2, numpy pairwise order
//   270344 : float  WT[64*1024]       (262144)  transposed codebook WT[i][k]
//   532488 : double adjd[1024]        (8192)    fp64 adjusted cluster size
// zeroed region = first 266248 bytes

// ---- prep: s_w in numpy scalar-pairwise order (identical to passing r2 code) ----
__global__ __launch_bounds__(256) void vq_prep_kernel(
    const float* __restrict__ emb, float* __restrict__ s_w)
{
    int k = blockIdx.x * 256 + threadIdx.x;   // grid 4*256 = 1024 codes
    const float* v = emb + k * DIMV;
    float r[8];
    #pragma unroll
    for (int j = 0; j < 8; ++j) {
        float sq = v[j] * v[j];
        asm("" : "+v"(sq));
        r[j] = sq;
    }
    #pragma unroll
    for (int m = 1; m < 8; ++m) {
        #pragma unroll
        for (int j = 0; j < 8; ++j) {
            float sq = v[8 * m + j] * v[8 * m + j];
            asm("" : "+v"(sq));
            r[j] += sq;
        }
    }
    s_w[k] = ((r[0] + r[1]) + (r[2] + r[3])) + ((r[4] + r[5]) + (r[6] + r[7]));
}

// ---- prep: transpose codebook so B-tile loads are coalesced ----
__global__ __launch_bounds__(64) void vq_transpose_kernel(
    const float* __restrict__ emb, float* __restrict__ WT)
{
    int k = blockIdx.x, t = threadIdx.x;
    WT[t * KCODES + k] = emb[k * DIMV + t];
}

// ---- main: tiled GEMM-style distance + argmin + epilogue ----
__global__ __launch_bounds__(256, 2) void vq_assign_kernel(
    const float* __restrict__ inp, const float* __restrict__ emb,
    const float* __restrict__ WT, const float* __restrict__ s_w,
    float* __restrict__ q_out, float* __restrict__ enc_out,
    double* __restrict__ loss_sum, int* __restrict__ counts,
    float* __restrict__ dw)
{
    __shared__ __align__(16) float At[64][128];   // g = 2f, [channel i][row r]
    __shared__ __align__(16) float Bt[64][128];   // codebook tile, [i][kk]
    __shared__ float sfL[128];
    __shared__ double lred[256];

    const int t  = threadIdx.x;
    const int tx = t & 15, ty = t >> 4;
    const int n0 = blockIdx.x * 128;
    const int bq  = n0 >> 12;          // batch index (stripe never crosses batch)
    const int hw0 = n0 & 4095;
    const float* fin = inp + (size_t)bq * (DIMV * HWSZ) + hw0;

    // ---- stage A: g = 2f into At[i][r], coalesced float2 loads ----
    {
        int l = t & 63, ib = t >> 6;   // ib in 0..3
        #pragma unroll
        for (int i2 = 0; i2 < 16; ++i2) {
            int i = i2 * 4 + ib;
            float2 v = *(const float2*)(fin + (size_t)i * HWSZ + 2 * l);
            At[i][2 * l]     = v.x + v.x;
            At[i][2 * l + 1] = v.y + v.y;
        }
    }
    __syncthreads();

    // ---- sf per row: numpy scalar-pairwise on f = 0.5*g (verbatim r2 math) ----
    if (t < 128) {
        float r8[8];
        #pragma unroll
        for (int j = 0; j < 8; ++j) {
            float h = 0.5f * At[j][t];
            float sq = h * h;
            asm("" : "+v"(sq));
            r8[j] = sq;
        }
        #pragma unroll
        for (int m = 1; m < 8; ++m) {
            #pragma unroll
            for (int j = 0; j < 8; ++j) {
                float h = 0.5f * At[8 * m + j][t];
                float sq = h * h;
                asm("" : "+v"(sq));
                r8[j] += sq;
            }
        }
        sfL[t] = ((r8[0] + r8[1]) + (r8[2] + r8[3])) + ((r8[4] + r8[5]) + (r8[6] + r8[7]));
    }
    __syncthreads();

    int rows[8];
    #pragma unroll
    for (int j = 0; j < 4; ++j) { rows[j] = 4 * ty + j; rows[4 + j] = 64 + 4 * ty + j; }
    float sfr[8];
    #pragma unroll
    for (int j = 0; j < 8; ++j) sfr[j] = sfL[rows[j]];

    float bestv[8]; int bestk[8];
    #pragma unroll
    for (int j = 0; j < 8; ++j) { bestv[j] = 3.0e38f; bestk[j] = 0; }

    const float4* WT4 = (const float4*)WT;   // [64][256] in float4 units

    for (int kt = 0; kt < 8; ++kt) {
        __syncthreads();   // previous tile's Bt reads done
        #pragma unroll
        for (int c = 0; c < 8; ++c) {
            int idx4 = c * 256 + t;
            int i = idx4 >> 5, kk4 = idx4 & 31;
            float4 v = WT4[i * 256 + kt * 32 + kk4];
            *(float4*)&Bt[i][kk4 * 4] = v;
        }
        __syncthreads();

        float acc[8][8];
        #pragma unroll
        for (int r = 0; r < 8; ++r)
            #pragma unroll
            for (int c = 0; c < 8; ++c) acc[r][c] = 0.0f;

        #pragma unroll 2
        for (int i = 0; i < 64; ++i) {
            float4 a0 = *(const float4*)&At[i][4 * ty];
            float4 a1 = *(const float4*)&At[i][64 + 4 * ty];
            float4 b0 = *(const float4*)&Bt[i][4 * tx];
            float4 b1 = *(const float4*)&Bt[i][64 + 4 * tx];
            float av[8] = {a0.x, a0.y, a0.z, a0.w, a1.x, a1.y, a1.z, a1.w};
            float bv[8] = {b0.x, b0.y, b0.z, b0.w, b1.x, b1.y, b1.z, b1.w};
            #pragma unroll
            for (int r = 0; r < 8; ++r)
                #pragma unroll
                for (int c = 0; c < 8; ++c)
                    acc[r][c] = __builtin_fmaf(av[r], bv[c], acc[r][c]);
        }

        float4 sw0 = *(const float4*)&s_w[kt * 128 + 4 * tx];
        float4 sw1 = *(const float4*)&s_w[kt * 128 + 64 + 4 * tx];
        float swv[8] = {sw0.x, sw0.y, sw0.z, sw0.w, sw1.x, sw1.y, sw1.z, sw1.w};
        int kb0 = kt * 128 + 4 * tx;
        int kb1 = kt * 128 + 64 + 4 * tx;
        #pragma unroll
        for (int c = 0; c < 8; ++c) {        // ascending k within thread
            int kg = (c < 4) ? (kb0 + c) : (kb1 + (c - 4));
            #pragma unroll
            for (int r = 0; r < 8; ++r) {
                float d = (sfr[r] - acc[r][c]) + swv[c];
                if (d < bestv[r]) { bestv[r] = d; bestk[r] = kg; }
            }
        }
    }

    // ---- cross-thread argmin reduction (overlay on Bt) ----
    __syncthreads();
    float* bvv = &Bt[0][0];          // [128][16] floats (8 KB)
    int*   bii = (int*)&Bt[16][0];   // [128][16] ints   (8 KB)
    #pragma unroll
    for (int j = 0; j < 8; ++j) {
        bvv[rows[j] * 16 + tx] = bestv[j];
        bii[rows[j] * 16 + tx] = bestk[j];
    }
    __syncthreads();

    double l = 0.0;
    if (t < 128) {
        int r = t;
        float bv = bvv[r * 16];
        int   bk = bii[r * 16];
        #pragma unroll
        for (int x = 1; x < 16; ++x) {
            float v = bvv[r * 16 + x];
            int   k = bii[r * 16 + x];
            if (v < bv || (v == bv && k < bk)) { bv = v; bk = k; }
        }

        int n = n0 + r;
        enc_out[n] = (float)bk;
        atomicAdd(&counts[bk], 1);

        const float* wrow = emb + bk * DIMV;
        float* qo = q_out + (size_t)bq * (DIMV * HWSZ) + hw0 + r;
        #pragma unroll
        for (int i = 0; i < DIMV; ++i) {
            float q = wrow[i];
            qo[(size_t)i * HWSZ] = q;
            float h = 0.5f * At[i][r];
            double dq = (double)q - (double)h;
            l = fma(dq, dq, l);
            atomicAdd(&dw[bk * DIMV + i], h);
        }
    }
    lred[t] = l;
    __syncthreads();
    #pragma unroll
    for (int off = 128; off > 0; off >>= 1) {
        if (t < off) lred[t] += lred[t + off];
        __syncthreads();
    }
    if (t == 0) atomicAdd(loss_sum, lred[0]);
}

// ---- finalize A: cluster sizes, normalization, loss ----
__global__ __launch_bounds__(1024) void vq_finalizeA_kernel(
    const float* __restrict__ ema_cs, const int* __restrict__ counts,
    const double* __restrict__ loss_sum,
    float* __restrict__ out_loss, float* __restrict__ out_nll,
    float* __restrict__ out_ncs, double* __restrict__ adjd)
{
    int k = threadIdx.x;
    const double DECAY = 0.99;
    const double OMD   = 1.0 - 0.99;
    const double EPSV  = 1e-5;

    double ncs = (double)ema_cs[k] * DECAY + OMD * (double)counts[k];

    __shared__ double sm[1024];
    sm[k] = ncs;
    __syncthreads();
    #pragma unroll
    for (int off = 512; off > 0; off >>= 1) {
        if (k < off) sm[k] += sm[k + off];
        __syncthreads();
    }
    double nsum = sm[0];
    double adj = (ncs + EPSV) / (nsum + (double)KCODES * EPSV) * nsum;
    out_ncs[k] = (float)adj;
    adjd[k] = adj;

    if (k == 0) {
        double e = loss_sum[0] / (double)NELEM;
        out_loss[0] = (float)(e + 0.25 * e);
        out_nll[0]  = 1.0f;
    }
}

// ---- finalize B: EMA weights + normalized embedding ----
__global__ __launch_bounds__(256) void vq_finalizeB_kernel(
    const float* __restrict__ ema_w, const float* __restrict__ dw,
    const double* __restrict__ adjd,
    float* __restrict__ out_nema, float* __restrict__ out_nemb)
{
    int idx = blockIdx.x * 256 + threadIdx.x;   // 65536 total
    int k = idx >> 6;
    const double DECAY = 0.99;
    const double OMD   = 1.0 - 0.99;
    double ne = (double)ema_w[idx] * DECAY + OMD * (double)dw[idx];
    out_nema[idx] = (float)ne;
    out_nemb[idx] = (float)(ne / adjd[k]);
}

extern "C" void kernel_launch(void* const* d_in, const int* in_sizes, int n_in,
                              void* d_out, int out_size, void* d_ws, size_t ws_size,
                              hipStream_t stream) {
    const float* inp    = (const float*)d_in[0];  // (32,64,64,64) NCHW
    const float* emb    = (const float*)d_in[1];  // (1024,64)
    const float* ema_cs = (const float*)d_in[2];  // (1024,)
    const float* ema_w  = (const float*)d_in[3];  // (1024,64)

    char* ws = (char*)d_ws;
    double* loss_sum = (double*)(ws + 0);
    int*    counts   = (int*)   (ws + 8);
    float*  dw       = (float*) (ws + 4104);
    float*  s_w      = (float*) (ws + 266248);
    float*  WT       = (float*) (ws + 270344);
    double* adjd     = (double*)(ws + 532488);

    float* out       = (float*)d_out;
    float* q_out     = out;                       // 8388608
    float* enc_out   = out + 8388608;             // 131072
    float* out_loss  = out + 8519680;             // 1
    float* out_nll   = out + 8519681;             // 1
    float* out_ncs   = out + 8519682;             // 1024
    float* out_nema  = out + 8520706;             // 65536
    float* out_nemb  = out + 8586242;             // 65536

    hipMemsetAsync(ws, 0, 266248, stream);
    hipLaunchKernelGGL(vq_prep_kernel, dim3(4), dim3(256), 0, stream, emb, s_w);
    hipLaunchKernelGGL(vq_transpose_kernel, dim3(KCODES), dim3(64), 0, stream, emb, WT);
    hipLaunchKernelGGL(vq_assign_kernel, dim3(NROWS / 128), dim3(256), 0, stream,
                       inp, emb, WT, s_w, q_out, enc_out, loss_sum, counts, dw);
    hipLaunchKernelGGL(vq_finalizeA_kernel, dim3(1), dim3(1024), 0, stream,
                       ema_cs, counts, loss_sum, out_loss, out_nll, out_ncs, adjd);
    hipLaunchKernelGGL(vq_finalizeB_kernel, dim3(256), dim3(256), 0, stream,
                       ema_w, dw, adjd, out_nema, out_nemb);
}